// Round 11
// baseline (494.123 us; speedup 1.0000x reference)
//
#include <hip/hip_runtime.h>
#include <hip/hip_bf16.h>
#include <hip/hip_fp16.h>

// NeuralNetwork_85255100825763
// conv1+bn+relu+pool -> conv2+bn+relu+pool -> MLP+softmax gate
// -> 8x LSTM(128) over 256 steps -> gated mean -> output proj.
//
// LSTM v11 (MFMA, type-split): R10 verified the MFMA path numerically but
// spilled (demand ~122 regs vs grant 88) -> per-iter scratch reloads, 441us.
// v11 halves the footprint: 16 waves, wave pair (2q,2q+1) owns j-tile q;
// even wave computes gate types {i,f}, odd {g,o} (A-frags = 32 VGPRs).
// Finished (bias-applied) gates for the partner's rows are exchanged via a
// lane-contiguous LDS buffer (1 b128 write + 1 read per wave per step).
// Even wave updates cells r=0,1; odd wave r=2,3. Class stride fixed (32768).

typedef _Float16 h2_t  __attribute__((ext_vector_type(2)));
typedef _Float16 f16x8 __attribute__((ext_vector_type(8)));
typedef float    f32x4 __attribute__((ext_vector_type(4)));
typedef unsigned int u32x4 __attribute__((ext_vector_type(4)));

__device__ __forceinline__ float dot2f(unsigned int w, unsigned int h, float acc) {
    return __builtin_amdgcn_fdot2(__builtin_bit_cast(h2_t, w),
                                  __builtin_bit_cast(h2_t, h), acc, false);
}
__device__ __forceinline__ float sigmoidf_(float x) {
    return 1.0f / (1.0f + __expf(-x));
}
__device__ __forceinline__ float tanhf_(float x) {
    float t = __expf(-2.0f * fabsf(x));   // in (0,1], no overflow
    float r = (1.0f - t) / (1.0f + t);
    return copysignf(r, x);
}
__device__ __forceinline__ unsigned short f2h(float x) {
    __half h = __float2half(x);           // RTNE
    return *(unsigned short*)&h;
}
__device__ __forceinline__ f32x4 mf(u32x4 a, u32x4 b, f32x4 c) {
    return __builtin_amdgcn_mfma_f32_16x16x32_f16(
        __builtin_bit_cast(f16x8, a), __builtin_bit_cast(f16x8, b), c, 0, 0, 0);
}

// ---------------- Kernel 0a: whh fp32 -> packed fp16 pairs (uint)
__global__ __launch_bounds__(256) void k_cvt(
    const float* __restrict__ w, unsigned int* __restrict__ wh)
{
    int i = blockIdx.x * 256 + threadIdx.x;     // 262144 pairs
    float2 f = ((const float2*)w)[i];
    wh[i] = (unsigned int)f2h(f.x) | ((unsigned int)f2h(f.y) << 16);
}

// ---------------- Kernel 0b: packed (bias, xw) fp16 per gate row
__global__ __launch_bounds__(256) void k_bx(
    const float* __restrict__ wih, const float* __restrict__ bih,
    const float* __restrict__ bhh, unsigned int* __restrict__ bx)
{
    int i = blockIdx.x * 256 + threadIdx.x;     // 4096 = 8*512
    float bias = bih[i] + bhh[i];
    bx[i] = (unsigned int)f2h(bias) | ((unsigned int)f2h(wih[i]) << 16);
}

// ---------------- Kernel 1: conv1 + bn1 + relu + maxpool2 -> c1 (64,16,64,64)
__global__ __launch_bounds__(256) void k_conv1(
    const float* __restrict__ x, const float* __restrict__ w,
    const float* __restrict__ cb, const float* __restrict__ g,
    const float* __restrict__ bb, const float* __restrict__ m,
    const float* __restrict__ v, float* __restrict__ c1)
{
    __shared__ __align__(16) float w1s[192];
    __shared__ float As[16], Cs[16];
    int tid = threadIdx.x;
    if (tid < 192) w1s[tid] = w[tid];
    if (tid < 16) {
        float s = g[tid] / sqrtf(v[tid] + 1e-5f);
        As[tid] = s;
        Cs[tid] = (cb[tid] - m[tid]) * s + bb[tid];
    }
    __syncthreads();

    int gid = blockIdx.x * 256 + tid;
    int b   = gid >> 12;
    int rem = gid & 4095;
    int oi  = rem >> 6, oj = rem & 63;

    float xr[3][4][4];
    #pragma unroll
    for (int ci = 0; ci < 3; ++ci) {
        #pragma unroll
        for (int r = 0; r < 4; ++r) {
            const float4 t4 = *(const float4*)(x +
                (((size_t)(b * 3 + ci) * 256 + (4 * oi + r)) * 256 + 4 * oj));
            xr[ci][r][0] = t4.x; xr[ci][r][1] = t4.y;
            xr[ci][r][2] = t4.z; xr[ci][r][3] = t4.w;
        }
    }
    const float4* w4 = (const float4*)w1s;
    #pragma unroll
    for (int co = 0; co < 16; ++co) {
        float val[2][2] = {{0.f, 0.f}, {0.f, 0.f}};
        #pragma unroll
        for (int ci = 0; ci < 3; ++ci) {
            float4 wq = w4[co * 3 + ci];
            #pragma unroll
            for (int pi = 0; pi < 2; ++pi) {
                #pragma unroll
                for (int pj = 0; pj < 2; ++pj) {
                    float a = val[pi][pj];
                    a = fmaf(xr[ci][2*pi  ][2*pj  ], wq.x, a);
                    a = fmaf(xr[ci][2*pi  ][2*pj+1], wq.y, a);
                    a = fmaf(xr[ci][2*pi+1][2*pj  ], wq.z, a);
                    a = fmaf(xr[ci][2*pi+1][2*pj+1], wq.w, a);
                    val[pi][pj] = a;
                }
            }
        }
        float A = As[co], C = Cs[co];
        float mx = 0.0f;
        #pragma unroll
        for (int pi = 0; pi < 2; ++pi)
            #pragma unroll
            for (int pj = 0; pj < 2; ++pj)
                mx = fmaxf(mx, fmaf(A, val[pi][pj], C));
        c1[((size_t)(b * 16 + co) * 64 + oi) * 64 + oj] = mx;
    }
}

// ---------------- Kernel 2: conv2 + bn2 + relu + maxpool2 -> c (64,256)
__global__ __launch_bounds__(256) void k_conv2(
    const float* __restrict__ c1, const float* __restrict__ w2,
    const float* __restrict__ cb, const float* __restrict__ g,
    const float* __restrict__ bb, const float* __restrict__ m,
    const float* __restrict__ v, float* __restrict__ c)
{
    __shared__ float w2s[64];
    int tid = threadIdx.x;
    if (tid < 64) w2s[tid] = w2[tid];
    __syncthreads();
    float A2 = g[0] / sqrtf(v[0] + 1e-5f);
    float C2 = (cb[0] - m[0]) * A2 + bb[0];

    int gid = blockIdx.x * 256 + tid;
    int b   = gid >> 8;
    int rem = gid & 255;
    int oi  = rem >> 4, oj = rem & 15;

    float val[2][2] = {{0.f, 0.f}, {0.f, 0.f}};
    for (int ci = 0; ci < 16; ++ci) {
        float xr[4][4];
        #pragma unroll
        for (int r = 0; r < 4; ++r) {
            float4 t4 = *(const float4*)(c1 +
                (((size_t)(b * 16 + ci) * 64 + (4 * oi + r)) * 64 + 4 * oj));
            xr[r][0] = t4.x; xr[r][1] = t4.y; xr[r][2] = t4.z; xr[r][3] = t4.w;
        }
        float w0 = w2s[ci*4+0], w1 = w2s[ci*4+1], w2v = w2s[ci*4+2], w3 = w2s[ci*4+3];
        #pragma unroll
        for (int pi = 0; pi < 2; ++pi) {
            #pragma unroll
            for (int pj = 0; pj < 2; ++pj) {
                float a = val[pi][pj];
                a = fmaf(xr[2*pi  ][2*pj  ], w0, a);
                a = fmaf(xr[2*pi  ][2*pj+1], w1, a);
                a = fmaf(xr[2*pi+1][2*pj  ], w2v, a);
                a = fmaf(xr[2*pi+1][2*pj+1], w3, a);
                val[pi][pj] = a;
            }
        }
    }
    float mx = 0.0f;
    #pragma unroll
    for (int pi = 0; pi < 2; ++pi)
        #pragma unroll
        for (int pj = 0; pj < 2; ++pj)
            mx = fmaxf(mx, fmaf(A2, val[pi][pj], C2));
    c[(size_t)b * 256 + oi * 16 + oj] = mx;
}

// ---------------- Kernel 3: MLP + softmax -> S (64,8) row-major flat
__global__ __launch_bounds__(64) void k_mlp(
    const float* __restrict__ c,
    const float* __restrict__ w1, const float* __restrict__ b1,
    const float* __restrict__ w2, const float* __restrict__ b2,
    const float* __restrict__ w3, const float* __restrict__ b3,
    float* __restrict__ S)
{
    __shared__ __align__(16) float cs[256];
    __shared__ float h1s[32], h2s[32], ls[8];
    int b = blockIdx.x, tid = threadIdx.x;
    *(float4*)&cs[tid * 4] = *(const float4*)(c + (size_t)b * 256 + tid * 4);
    __syncthreads();
    if (tid < 32) {
        float acc = b1[tid];
        for (int k = 0; k < 256; ++k) acc = fmaf(cs[k], w1[tid * 256 + k], acc);
        h1s[tid] = fmaxf(acc, 0.f);
    }
    __syncthreads();
    if (tid < 32) {
        float acc = b2[tid];
        #pragma unroll
        for (int k = 0; k < 32; ++k) acc = fmaf(h1s[k], w2[tid * 32 + k], acc);
        h2s[tid] = fmaxf(acc, 0.f);
    }
    __syncthreads();
    if (tid < 8) {
        float acc = b3[tid];
        #pragma unroll
        for (int k = 0; k < 32; ++k) acc = fmaf(h2s[k], w3[tid * 32 + k], acc);
        ls[tid] = acc;
    }
    __syncthreads();
    if (tid == 0) {
        float mx = ls[0];
        #pragma unroll
        for (int k = 1; k < 8; ++k) mx = fmaxf(mx, ls[k]);
        float e[8]; float sum = 0.f;
        #pragma unroll
        for (int k = 0; k < 8; ++k) { e[k] = expf(ls[k] - mx); sum += e[k]; }
        float inv = 1.0f / sum;
        #pragma unroll
        for (int k = 0; k < 8; ++k) S[b * 8 + k] = e[k] * inv;
    }
}

// ---------------- Kernel 4: LSTM via MFMA, type-split.
// Block = (class, 16 batch rows), 1024 threads = 16 waves.
// Wave pair (2q,2q+1) owns j-tile q. hi=0 computes types {i,f}; hi=1 {g,o}.
// After bias epilogue, each ships the partner's rows' gates (1 b128 each way);
// hi=0 updates cells r=0,1; hi=1 updates r=2,3. 2 barriers/step.
__global__
__attribute__((amdgpu_flat_work_group_size(1024, 1024), amdgpu_waves_per_eu(4, 4)))
void k_lstm(
    const unsigned int* __restrict__ whh_h,  // fp16 pairs [8][512][64]
    const unsigned int* __restrict__ bx,     // packed (bias,xw) fp16 [8][512]
    const float* __restrict__ hn, const float* __restrict__ c,
    float* __restrict__ lasth)
{
    __shared__ __align__(16) unsigned short h_sw[2048];  // [16 n][128 k] fp16, byte^((n&7)<<4)
    __shared__ __align__(16) float c_l[4096];            // [256 t][16 n]
    __shared__ __align__(16) float xch[4096];            // [8 q][2 hi][64 lane] f32x4

    int tid  = threadIdx.x;
    int wv   = tid >> 6, lane = tid & 63;
    int q    = wv >> 1,  hi   = wv & 1;
    int lrow = lane & 15, lgrp = lane >> 4;
    int kcls = blockIdx.x >> 2;
    int bbase = (blockIdx.x & 3) * 16;

    // A fragments: 2 types x 4 K-slices = 8 u32x4 = 32 VGPRs.
    // Per-class stride = 512 rows * 64 pairs = 32768 u32.
    const unsigned int* wbase = whh_h + (size_t)kcls * 32768;
    int rA = ((hi*2 + 0)*128 + q*16 + lrow) * 64 + lgrp*4;   // type hi*2
    int rB = ((hi*2 + 1)*128 + q*16 + lrow) * 64 + lgrp*4;   // type hi*2+1
    u32x4 a00 = *(const u32x4*)(wbase+rA+ 0), a01 = *(const u32x4*)(wbase+rA+16),
          a02 = *(const u32x4*)(wbase+rA+32), a03 = *(const u32x4*)(wbase+rA+48);
    u32x4 a10 = *(const u32x4*)(wbase+rB+ 0), a11 = *(const u32x4*)(wbase+rB+16),
          a12 = *(const u32x4*)(wbase+rB+32), a13 = *(const u32x4*)(wbase+rB+48);
    asm volatile("" : "+v"(a00), "+v"(a01), "+v"(a02), "+v"(a03),
                      "+v"(a10), "+v"(a11), "+v"(a12), "+v"(a13));

    // packed (bias,xw) for this lane's 4 C-rows, both owned types
    const unsigned int* bxp = bx + kcls * 512;
    u32x4 bxa = *(const u32x4*)(bxp + (hi*2 + 0)*128 + q*16 + lgrp*4);
    u32x4 bxb = *(const u32x4*)(bxp + (hi*2 + 1)*128 + q*16 + lgrp*4);

    // init h_sw (swizzled fp16): 1024 u32 writes, one per thread
    {
        int n = tid >> 6, j0 = (tid & 63) * 2;
        const float* hp = hn + ((size_t)kcls*64 + bbase + n)*128 + j0;
        unsigned int pk = (unsigned int)f2h(hp[0]) | ((unsigned int)f2h(hp[1]) << 16);
        *(unsigned int*)((char*)h_sw + ((n*256 + j0*2) ^ ((n & 7) << 4))) = pk;
    }
    #pragma unroll
    for (int i = 0; i < 4; ++i) {
        int idx = tid + i*1024;
        int n = idx >> 8, t = idx & 255;
        c_l[t*16 + n] = c[(size_t)(bbase + n)*256 + t];
    }
    float cc0 = 0.f, cc1 = 0.f;
    __syncthreads();

    int  swz = (lrow & 7) << 4;
    int  hb  = lrow*256 + lgrp*16;
    int  hw  = (lrow*256 + (q*16 + lgrp*4 + hi*2)*2) ^ swz;  // this lane's 2 rows
    int  xw_off = q*2048 + hi*1024 + lane*16;                // bytes, lane-contiguous
    int  xr_off = q*2048 + (hi^1)*1024 + lane*16;
    bool dolast = (wv == 15) && (lgrp == 3);                 // q=7, hi=1, r=3 -> j=127
    float* lastp = lasth + ((size_t)kcls*64 + bbase + lrow)*256;

    for (int t = 0; t < 256; ++t) {
        u32x4 b0 = *(const u32x4*)((char*)h_sw + ((hb +   0) ^ swz));
        u32x4 b1 = *(const u32x4*)((char*)h_sw + ((hb +  64) ^ swz));
        u32x4 b2 = *(const u32x4*)((char*)h_sw + ((hb + 128) ^ swz));
        u32x4 b3 = *(const u32x4*)((char*)h_sw + ((hb + 192) ^ swz));
        f32x4 d0 = {0.f,0.f,0.f,0.f}, d1 = {0.f,0.f,0.f,0.f};
        d0 = mf(a00,b0,d0); d1 = mf(a10,b0,d1);
        d0 = mf(a01,b1,d0); d1 = mf(a11,b1,d1);
        d0 = mf(a02,b2,d0); d1 = mf(a12,b2,d1);
        d0 = mf(a03,b3,d0); d1 = mf(a13,b3,d1);

        // bias + xw*c_t epilogue (applied by the type owner for all 4 rows)
        float ct = c_l[t*16 + lrow];
        unsigned int pk2 = 0x3c00u | ((unsigned int)f2h(ct) << 16);  // (1.0, ct)
        d0[0] = dot2f(bxa[0], pk2, d0[0]); d0[1] = dot2f(bxa[1], pk2, d0[1]);
        d0[2] = dot2f(bxa[2], pk2, d0[2]); d0[3] = dot2f(bxa[3], pk2, d0[3]);
        d1[0] = dot2f(bxb[0], pk2, d1[0]); d1[1] = dot2f(bxb[1], pk2, d1[1]);
        d1[2] = dot2f(bxb[2], pk2, d1[2]); d1[3] = dot2f(bxb[3], pk2, d1[3]);

        // ship partner's rows: hi=0 ships (i,f) of r2,r3; hi=1 ships (g,o) of r0,r1
        f32x4 sh;
        if (hi == 0) { sh[0]=d0[2]; sh[1]=d0[3]; sh[2]=d1[2]; sh[3]=d1[3]; }
        else         { sh[0]=d0[0]; sh[1]=d0[1]; sh[2]=d1[0]; sh[3]=d1[1]; }
        *(f32x4*)((char*)xch + xw_off) = sh;
        __syncthreads();   // xch visible; all h_sw reads of step t done

        f32x4 pv = *(const f32x4*)((char*)xch + xr_off);
        float gi0, gf0, gg0, go0, gi1, gf1, gg1, go1;
        if (hi == 0) {     // cells r=0,1: own i,f ; partner (g,o) for r0,r1
            gi0 = d0[0]; gf0 = d1[0]; gg0 = pv[0]; go0 = pv[2];
            gi1 = d0[1]; gf1 = d1[1]; gg1 = pv[1]; go1 = pv[3];
        } else {           // cells r=2,3: partner (i,f) for r2,r3 ; own g,o
            gi0 = pv[0]; gf0 = pv[2]; gg0 = d0[2]; go0 = d1[2];
            gi1 = pv[1]; gf1 = pv[3]; gg1 = d0[3]; go1 = d1[3];
        }
        cc0 = sigmoidf_(gf0)*cc0 + sigmoidf_(gi0)*tanhf_(gg0);
        float h0 = sigmoidf_(go0)*tanhf_(cc0);
        cc1 = sigmoidf_(gf1)*cc1 + sigmoidf_(gi1)*tanhf_(gg1);
        float h1 = sigmoidf_(go1)*tanhf_(cc1);
        unsigned int hpk = (unsigned int)f2h(h0) | ((unsigned int)f2h(h1) << 16);
        *(unsigned int*)((char*)h_sw + hw) = hpk;
        if (dolast) lastp[t] = h1;   // j = 127
        __syncthreads();   // new h visible; xch reads done
    }
}

// ---------------- Kernel 5: gated mean over classes + output projection
__global__ __launch_bounds__(256) void k_out(
    const float* __restrict__ lasth, const float* __restrict__ S,
    const float* __restrict__ out_w, const float* __restrict__ out_b,
    float* __restrict__ out)
{
    __shared__ __align__(16) float avg[256];
    int b = blockIdx.x, t = threadIdx.x;
    float a = 0.f;
    #pragma unroll
    for (int k = 0; k < 8; ++k) {
        // pre.reshape(NCLS,B,1): weight(k,b) = S_flat[k*64+b]
        a = fmaf(S[k * 64 + b], lasth[((size_t)k * 64 + b) * 256 + t], a);
    }
    avg[t] = a * 0.125f;
    __syncthreads();
    if (t < 8) {
        float acc = out_b[t];
        for (int tt = 0; tt < 256; ++tt)
            acc = fmaf(avg[tt], out_w[t * 256 + tt], acc);
        out[b * 8 + t] = acc;
    }
}

extern "C" void kernel_launch(void* const* d_in, const int* in_sizes, int n_in,
                              void* d_out, int out_size, void* d_ws, size_t ws_size,
                              hipStream_t stream) {
    const float* x       = (const float*)d_in[0];
    const float* conv1_w = (const float*)d_in[1];
    const float* conv1_b = (const float*)d_in[2];
    const float* bn1_g   = (const float*)d_in[3];
    const float* bn1_b   = (const float*)d_in[4];
    const float* bn1_m   = (const float*)d_in[5];
    const float* bn1_v   = (const float*)d_in[6];
    const float* conv2_w = (const float*)d_in[7];
    const float* conv2_b = (const float*)d_in[8];
    const float* bn2_g   = (const float*)d_in[9];
    const float* bn2_b   = (const float*)d_in[10];
    const float* bn2_m   = (const float*)d_in[11];
    const float* bn2_v   = (const float*)d_in[12];
    const float* pre_w1  = (const float*)d_in[13];
    const float* pre_b1  = (const float*)d_in[14];
    const float* pre_w2  = (const float*)d_in[15];
    const float* pre_b2  = (const float*)d_in[16];
    const float* pre_w3  = (const float*)d_in[17];
    const float* pre_b3  = (const float*)d_in[18];
    const float* lstm_wih = (const float*)d_in[19];
    const float* lstm_whh = (const float*)d_in[20];
    const float* lstm_bih = (const float*)d_in[21];
    const float* lstm_bhh = (const float*)d_in[22];
    const float* hn      = (const float*)d_in[23];
    const float* out_w   = (const float*)d_in[24];
    const float* out_b   = (const float*)d_in[25];

    float* ws    = (float*)d_ws;
    float* c1    = ws;                       // 64*16*64*64 = 4194304 floats
    float* c     = c1 + 4194304;             // 64*256
    float* S     = c + 16384;                // 64*8
    float* lasth = S + 512;                  // 8*64*256
    // After conv2, the c1 region is dead; reuse it for converted weights.
    unsigned int* whh_h = (unsigned int*)c1;           // 262144 u32 = 1 MB
    unsigned int* bx    = whh_h + 262144;              // 4096 u32

    k_conv1<<<1024, 256, 0, stream>>>(x, conv1_w, conv1_b, bn1_g, bn1_b, bn1_m, bn1_v, c1);
    k_conv2<<<64, 256, 0, stream>>>(c1, conv2_w, conv2_b, bn2_g, bn2_b, bn2_m, bn2_v, c);
    k_mlp<<<64, 64, 0, stream>>>(c, pre_w1, pre_b1, pre_w2, pre_b2, pre_w3, pre_b3, S);
    k_cvt<<<1024, 256, 0, stream>>>(lstm_whh, whh_h);
    k_bx<<<16, 256, 0, stream>>>(lstm_wih, lstm_bih, lstm_bhh, bx);
    k_lstm<<<32, 1024, 0, stream>>>(whh_h, bx, hn, c, lasth);
    k_out<<<64, 256, 0, stream>>>(lasth, S, out_w, out_b, (float*)d_out);
}

// Round 12
// 463.123 us; speedup vs baseline: 1.0669x; 1.0669x over previous
//
#include <hip/hip_runtime.h>
#include <hip/hip_bf16.h>
#include <hip/hip_fp16.h>

// NeuralNetwork_85255100825763
// conv1+bn+relu+pool -> conv2+bn+relu+pool -> MLP+softmax gate
// -> 8x LSTM(128) over 256 steps -> gated mean -> output proj.
//
// LSTM v12 (MFMA + AGPR weights): R10/R11 proved the MFMA path numerically
// but the VGPR allocator grants only 48-88 arch-VGPRs no matter the
// attributes -> weight fragments spilled, per-iter scratch reloads, 440+us.
// v12 stores the 16 weight quads in AGPRs ("+a" asm pin, once, outside the
// loop): gfx950 MFMA reads A directly from AGPRs (ISA: A,B from VGPR or
// AGPR), so the weights never touch the constrained VGPR segment. In-loop
// VGPR demand ~60 < any observed grant. Geometry = R10 (verified):
// 8 waves/block, wave owns j-tile q with all 4 gate types, thread-local
// cell update, swizzled fp16 h-LDS, packed (bias,xw) dot2 epilogue.

typedef _Float16 h2_t  __attribute__((ext_vector_type(2)));
typedef _Float16 f16x8 __attribute__((ext_vector_type(8)));
typedef float    f32x4 __attribute__((ext_vector_type(4)));
typedef unsigned int u32x2 __attribute__((ext_vector_type(2)));
typedef unsigned int u32x4 __attribute__((ext_vector_type(4)));

__device__ __forceinline__ float dot2f(unsigned int w, unsigned int h, float acc) {
    return __builtin_amdgcn_fdot2(__builtin_bit_cast(h2_t, w),
                                  __builtin_bit_cast(h2_t, h), acc, false);
}
__device__ __forceinline__ float sigmoidf_(float x) {
    return 1.0f / (1.0f + __expf(-x));
}
__device__ __forceinline__ float tanhf_(float x) {
    float t = __expf(-2.0f * fabsf(x));   // in (0,1], no overflow
    float r = (1.0f - t) / (1.0f + t);
    return copysignf(r, x);
}
__device__ __forceinline__ unsigned short f2h(float x) {
    __half h = __float2half(x);           // RTNE
    return *(unsigned short*)&h;
}
__device__ __forceinline__ f32x4 mf(u32x4 a, u32x4 b, f32x4 c) {
    return __builtin_amdgcn_mfma_f32_16x16x32_f16(
        __builtin_bit_cast(f16x8, a), __builtin_bit_cast(f16x8, b), c, 0, 0, 0);
}

// ---------------- Kernel 0a: whh fp32 -> packed fp16 pairs (uint)
__global__ __launch_bounds__(256) void k_cvt(
    const float* __restrict__ w, unsigned int* __restrict__ wh)
{
    int i = blockIdx.x * 256 + threadIdx.x;     // 262144 pairs
    float2 f = ((const float2*)w)[i];
    wh[i] = (unsigned int)f2h(f.x) | ((unsigned int)f2h(f.y) << 16);
}

// ---------------- Kernel 0b: packed (bias, xw) fp16 per gate row
__global__ __launch_bounds__(256) void k_bx(
    const float* __restrict__ wih, const float* __restrict__ bih,
    const float* __restrict__ bhh, unsigned int* __restrict__ bx)
{
    int i = blockIdx.x * 256 + threadIdx.x;     // 4096 = 8*512
    float bias = bih[i] + bhh[i];
    bx[i] = (unsigned int)f2h(bias) | ((unsigned int)f2h(wih[i]) << 16);
}

// ---------------- Kernel 1: conv1 + bn1 + relu + maxpool2 -> c1 (64,16,64,64)
__global__ __launch_bounds__(256) void k_conv1(
    const float* __restrict__ x, const float* __restrict__ w,
    const float* __restrict__ cb, const float* __restrict__ g,
    const float* __restrict__ bb, const float* __restrict__ m,
    const float* __restrict__ v, float* __restrict__ c1)
{
    __shared__ __align__(16) float w1s[192];
    __shared__ float As[16], Cs[16];
    int tid = threadIdx.x;
    if (tid < 192) w1s[tid] = w[tid];
    if (tid < 16) {
        float s = g[tid] / sqrtf(v[tid] + 1e-5f);
        As[tid] = s;
        Cs[tid] = (cb[tid] - m[tid]) * s + bb[tid];
    }
    __syncthreads();

    int gid = blockIdx.x * 256 + tid;
    int b   = gid >> 12;
    int rem = gid & 4095;
    int oi  = rem >> 6, oj = rem & 63;

    float xr[3][4][4];
    #pragma unroll
    for (int ci = 0; ci < 3; ++ci) {
        #pragma unroll
        for (int r = 0; r < 4; ++r) {
            const float4 t4 = *(const float4*)(x +
                (((size_t)(b * 3 + ci) * 256 + (4 * oi + r)) * 256 + 4 * oj));
            xr[ci][r][0] = t4.x; xr[ci][r][1] = t4.y;
            xr[ci][r][2] = t4.z; xr[ci][r][3] = t4.w;
        }
    }
    const float4* w4 = (const float4*)w1s;
    #pragma unroll
    for (int co = 0; co < 16; ++co) {
        float val[2][2] = {{0.f, 0.f}, {0.f, 0.f}};
        #pragma unroll
        for (int ci = 0; ci < 3; ++ci) {
            float4 wq = w4[co * 3 + ci];
            #pragma unroll
            for (int pi = 0; pi < 2; ++pi) {
                #pragma unroll
                for (int pj = 0; pj < 2; ++pj) {
                    float a = val[pi][pj];
                    a = fmaf(xr[ci][2*pi  ][2*pj  ], wq.x, a);
                    a = fmaf(xr[ci][2*pi  ][2*pj+1], wq.y, a);
                    a = fmaf(xr[ci][2*pi+1][2*pj  ], wq.z, a);
                    a = fmaf(xr[ci][2*pi+1][2*pj+1], wq.w, a);
                    val[pi][pj] = a;
                }
            }
        }
        float A = As[co], C = Cs[co];
        float mx = 0.0f;
        #pragma unroll
        for (int pi = 0; pi < 2; ++pi)
            #pragma unroll
            for (int pj = 0; pj < 2; ++pj)
                mx = fmaxf(mx, fmaf(A, val[pi][pj], C));
        c1[((size_t)(b * 16 + co) * 64 + oi) * 64 + oj] = mx;
    }
}

// ---------------- Kernel 2: conv2 + bn2 + relu + maxpool2 -> c (64,256)
__global__ __launch_bounds__(256) void k_conv2(
    const float* __restrict__ c1, const float* __restrict__ w2,
    const float* __restrict__ cb, const float* __restrict__ g,
    const float* __restrict__ bb, const float* __restrict__ m,
    const float* __restrict__ v, float* __restrict__ c)
{
    __shared__ float w2s[64];
    int tid = threadIdx.x;
    if (tid < 64) w2s[tid] = w2[tid];
    __syncthreads();
    float A2 = g[0] / sqrtf(v[0] + 1e-5f);
    float C2 = (cb[0] - m[0]) * A2 + bb[0];

    int gid = blockIdx.x * 256 + tid;
    int b   = gid >> 8;
    int rem = gid & 255;
    int oi  = rem >> 4, oj = rem & 15;

    float val[2][2] = {{0.f, 0.f}, {0.f, 0.f}};
    for (int ci = 0; ci < 16; ++ci) {
        float xr[4][4];
        #pragma unroll
        for (int r = 0; r < 4; ++r) {
            float4 t4 = *(const float4*)(c1 +
                (((size_t)(b * 16 + ci) * 64 + (4 * oi + r)) * 64 + 4 * oj));
            xr[r][0] = t4.x; xr[r][1] = t4.y; xr[r][2] = t4.z; xr[r][3] = t4.w;
        }
        float w0 = w2s[ci*4+0], w1 = w2s[ci*4+1], w2v = w2s[ci*4+2], w3 = w2s[ci*4+3];
        #pragma unroll
        for (int pi = 0; pi < 2; ++pi) {
            #pragma unroll
            for (int pj = 0; pj < 2; ++pj) {
                float a = val[pi][pj];
                a = fmaf(xr[2*pi  ][2*pj  ], w0, a);
                a = fmaf(xr[2*pi  ][2*pj+1], w1, a);
                a = fmaf(xr[2*pi+1][2*pj  ], w2v, a);
                a = fmaf(xr[2*pi+1][2*pj+1], w3, a);
                val[pi][pj] = a;
            }
        }
    }
    float mx = 0.0f;
    #pragma unroll
    for (int pi = 0; pi < 2; ++pi)
        #pragma unroll
        for (int pj = 0; pj < 2; ++pj)
            mx = fmaxf(mx, fmaf(A2, val[pi][pj], C2));
    c[(size_t)b * 256 + oi * 16 + oj] = mx;
}

// ---------------- Kernel 3: MLP + softmax -> S (64,8) row-major flat
__global__ __launch_bounds__(64) void k_mlp(
    const float* __restrict__ c,
    const float* __restrict__ w1, const float* __restrict__ b1,
    const float* __restrict__ w2, const float* __restrict__ b2,
    const float* __restrict__ w3, const float* __restrict__ b3,
    float* __restrict__ S)
{
    __shared__ __align__(16) float cs[256];
    __shared__ float h1s[32], h2s[32], ls[8];
    int b = blockIdx.x, tid = threadIdx.x;
    *(float4*)&cs[tid * 4] = *(const float4*)(c + (size_t)b * 256 + tid * 4);
    __syncthreads();
    if (tid < 32) {
        float acc = b1[tid];
        for (int k = 0; k < 256; ++k) acc = fmaf(cs[k], w1[tid * 256 + k], acc);
        h1s[tid] = fmaxf(acc, 0.f);
    }
    __syncthreads();
    if (tid < 32) {
        float acc = b2[tid];
        #pragma unroll
        for (int k = 0; k < 32; ++k) acc = fmaf(h1s[k], w2[tid * 32 + k], acc);
        h2s[tid] = fmaxf(acc, 0.f);
    }
    __syncthreads();
    if (tid < 8) {
        float acc = b3[tid];
        #pragma unroll
        for (int k = 0; k < 32; ++k) acc = fmaf(h2s[k], w3[tid * 32 + k], acc);
        ls[tid] = acc;
    }
    __syncthreads();
    if (tid == 0) {
        float mx = ls[0];
        #pragma unroll
        for (int k = 1; k < 8; ++k) mx = fmaxf(mx, ls[k]);
        float e[8]; float sum = 0.f;
        #pragma unroll
        for (int k = 0; k < 8; ++k) { e[k] = expf(ls[k] - mx); sum += e[k]; }
        float inv = 1.0f / sum;
        #pragma unroll
        for (int k = 0; k < 8; ++k) S[b * 8 + k] = e[k] * inv;
    }
}

// ---------------- Kernel 4: LSTM via MFMA, weights in AGPRs.
// Block = (class, 16 batch rows), 512 threads = 8 waves.
// Wave q owns j-tile q (16 hidden dims), all 4 gate types; thread-local update.
__global__
__attribute__((amdgpu_flat_work_group_size(512, 512), amdgpu_waves_per_eu(2, 2)))
void k_lstm(
    const unsigned int* __restrict__ whh_h,  // fp16 pairs [8][512][64]
    const unsigned int* __restrict__ bx,     // packed (bias,xw) fp16 [8][512]
    const float* __restrict__ hn, const float* __restrict__ c,
    float* __restrict__ lasth)
{
    __shared__ __align__(16) unsigned short h_sw[2048];  // [16 n][128 k] fp16, byte^((n&7)<<4)
    __shared__ __align__(16) float c_l[4096];            // [256 t][16 n]

    int tid  = threadIdx.x;
    int wv   = tid >> 6, lane = tid & 63;    // wv = q = j-tile index 0..7
    int lrow = lane & 15, lgrp = lane >> 4;
    int kcls = blockIdx.x >> 2;
    int bbase = (blockIdx.x & 3) * 16;

    // A fragments: 4 types x 4 K-slices = 16 u32x4. Stored in AGPRs:
    // the "+a" pin (once, outside the loop) forces AGPR class; gfx950 MFMA
    // reads A directly from AGPRs, so these never occupy arch-VGPRs.
    const unsigned int* wbase = whh_h + (size_t)kcls * 32768;
    int rI = (0*128 + wv*16 + lrow) * 64 + lgrp*4;
    int rF = (1*128 + wv*16 + lrow) * 64 + lgrp*4;
    int rG = (2*128 + wv*16 + lrow) * 64 + lgrp*4;
    int rO = (3*128 + wv*16 + lrow) * 64 + lgrp*4;
    u32x4 ai0 = *(const u32x4*)(wbase+rI+ 0), ai1 = *(const u32x4*)(wbase+rI+16),
          ai2 = *(const u32x4*)(wbase+rI+32), ai3 = *(const u32x4*)(wbase+rI+48);
    u32x4 af0 = *(const u32x4*)(wbase+rF+ 0), af1 = *(const u32x4*)(wbase+rF+16),
          af2 = *(const u32x4*)(wbase+rF+32), af3 = *(const u32x4*)(wbase+rF+48);
    u32x4 ag0 = *(const u32x4*)(wbase+rG+ 0), ag1 = *(const u32x4*)(wbase+rG+16),
          ag2 = *(const u32x4*)(wbase+rG+32), ag3 = *(const u32x4*)(wbase+rG+48);
    u32x4 ao0 = *(const u32x4*)(wbase+rO+ 0), ao1 = *(const u32x4*)(wbase+rO+16),
          ao2 = *(const u32x4*)(wbase+rO+32), ao3 = *(const u32x4*)(wbase+rO+48);
    asm volatile("" : "+a"(ai0), "+a"(ai1), "+a"(ai2), "+a"(ai3),
                      "+a"(af0), "+a"(af1), "+a"(af2), "+a"(af3));
    asm volatile("" : "+a"(ag0), "+a"(ag1), "+a"(ag2), "+a"(ag3),
                      "+a"(ao0), "+a"(ao1), "+a"(ao2), "+a"(ao3));

    const unsigned int* bxp = bx + kcls * 512;
    u32x4 bxi = *(const u32x4*)(bxp + 0*128 + wv*16 + lgrp*4);
    u32x4 bxf = *(const u32x4*)(bxp + 1*128 + wv*16 + lgrp*4);
    u32x4 bxg = *(const u32x4*)(bxp + 2*128 + wv*16 + lgrp*4);
    u32x4 bxq = *(const u32x4*)(bxp + 3*128 + wv*16 + lgrp*4);

    #pragma unroll
    for (int i = 0; i < 2; ++i) {
        int idx = tid + i*512;
        int n = idx >> 6, j0 = (idx & 63) * 2;
        const float* hp = hn + ((size_t)kcls*64 + bbase + n)*128 + j0;
        unsigned int pk = (unsigned int)f2h(hp[0]) | ((unsigned int)f2h(hp[1]) << 16);
        *(unsigned int*)((char*)h_sw + ((n*256 + j0*2) ^ ((n & 7) << 4))) = pk;
    }
    #pragma unroll
    for (int i = 0; i < 8; ++i) {
        int idx = tid + i*512;
        int n = idx >> 8, t = idx & 255;
        c_l[t*16 + n] = c[(size_t)(bbase + n)*256 + t];
    }
    float cc0 = 0.f, cc1 = 0.f, cc2 = 0.f, cc3 = 0.f;
    __syncthreads();

    int  swz = (lrow & 7) << 4;
    int  hb  = lrow*256 + lgrp*16;
    int  hw  = (lrow*256 + (wv*16 + lgrp*4)*2) ^ swz;
    bool dolast = (wv == 7) && (lgrp == 3);         // owns j=127 (r=3)
    float* lastp = lasth + ((size_t)kcls*64 + bbase + lrow)*256;

#define CELL(R, CC, HV)                                         \
    {                                                           \
        float gi = sigmoidf_(dot2f(bxi[R], pk2, di[R]));        \
        float gf = sigmoidf_(dot2f(bxf[R], pk2, df_[R]));       \
        float gg = tanhf_   (dot2f(bxg[R], pk2, dg[R]));        \
        float go = sigmoidf_(dot2f(bxq[R], pk2, dq[R]));        \
        CC = gf * CC + gi * gg;                                 \
        HV = go * tanhf_(CC);                                   \
    }

    for (int t = 0; t < 256; ++t) {
        u32x4 b0 = *(const u32x4*)((char*)h_sw + ((hb +   0) ^ swz));
        u32x4 b1 = *(const u32x4*)((char*)h_sw + ((hb +  64) ^ swz));
        u32x4 b2 = *(const u32x4*)((char*)h_sw + ((hb + 128) ^ swz));
        u32x4 b3 = *(const u32x4*)((char*)h_sw + ((hb + 192) ^ swz));
        f32x4 di  = {0.f,0.f,0.f,0.f}, df_ = {0.f,0.f,0.f,0.f};
        f32x4 dg  = {0.f,0.f,0.f,0.f}, dq  = {0.f,0.f,0.f,0.f};
        di = mf(ai0,b0,di); df_ = mf(af0,b0,df_); dg = mf(ag0,b0,dg); dq = mf(ao0,b0,dq);
        di = mf(ai1,b1,di); df_ = mf(af1,b1,df_); dg = mf(ag1,b1,dg); dq = mf(ao1,b1,dq);
        di = mf(ai2,b2,di); df_ = mf(af2,b2,df_); dg = mf(ag2,b2,dg); dq = mf(ao2,b2,dq);
        di = mf(ai3,b3,di); df_ = mf(af3,b3,df_); dg = mf(ag3,b3,dg); dq = mf(ao3,b3,dq);
        __syncthreads();   // all h_sw reads of step t complete

        float ct = c_l[t*16 + lrow];
        unsigned int pk2 = 0x3c00u | ((unsigned int)f2h(ct) << 16);  // (1.0, ct)
        float h0, h1, h2, h3;
        CELL(0, cc0, h0) CELL(1, cc1, h1) CELL(2, cc2, h2) CELL(3, cc3, h3)

        u32x2 hpk;
        hpk[0] = (unsigned int)f2h(h0) | ((unsigned int)f2h(h1) << 16);
        hpk[1] = (unsigned int)f2h(h2) | ((unsigned int)f2h(h3) << 16);
        *(u32x2*)((char*)h_sw + hw) = hpk;
        if (dolast) lastp[t] = h3;   // j = 127
        __syncthreads();   // new h visible
    }
#undef CELL
}

// ---------------- Kernel 5: gated mean over classes + output projection
__global__ __launch_bounds__(256) void k_out(
    const float* __restrict__ lasth, const float* __restrict__ S,
    const float* __restrict__ out_w, const float* __restrict__ out_b,
    float* __restrict__ out)
{
    __shared__ __align__(16) float avg[256];
    int b = blockIdx.x, t = threadIdx.x;
    float a = 0.f;
    #pragma unroll
    for (int k = 0; k < 8; ++k) {
        // pre.reshape(NCLS,B,1): weight(k,b) = S_flat[k*64+b]
        a = fmaf(S[k * 64 + b], lasth[((size_t)k * 64 + b) * 256 + t], a);
    }
    avg[t] = a * 0.125f;
    __syncthreads();
    if (t < 8) {
        float acc = out_b[t];
        for (int tt = 0; tt < 256; ++tt)
            acc = fmaf(avg[tt], out_w[t * 256 + tt], acc);
        out[b * 8 + t] = acc;
    }
}

extern "C" void kernel_launch(void* const* d_in, const int* in_sizes, int n_in,
                              void* d_out, int out_size, void* d_ws, size_t ws_size,
                              hipStream_t stream) {
    const float* x       = (const float*)d_in[0];
    const float* conv1_w = (const float*)d_in[1];
    const float* conv1_b = (const float*)d_in[2];
    const float* bn1_g   = (const float*)d_in[3];
    const float* bn1_b   = (const float*)d_in[4];
    const float* bn1_m   = (const float*)d_in[5];
    const float* bn1_v   = (const float*)d_in[6];
    const float* conv2_w = (const float*)d_in[7];
    const float* conv2_b = (const float*)d_in[8];
    const float* bn2_g   = (const float*)d_in[9];
    const float* bn2_b   = (const float*)d_in[10];
    const float* bn2_m   = (const float*)d_in[11];
    const float* bn2_v   = (const float*)d_in[12];
    const float* pre_w1  = (const float*)d_in[13];
    const float* pre_b1  = (const float*)d_in[14];
    const float* pre_w2  = (const float*)d_in[15];
    const float* pre_b2  = (const float*)d_in[16];
    const float* pre_w3  = (const float*)d_in[17];
    const float* pre_b3  = (const float*)d_in[18];
    const float* lstm_wih = (const float*)d_in[19];
    const float* lstm_whh = (const float*)d_in[20];
    const float* lstm_bih = (const float*)d_in[21];
    const float* lstm_bhh = (const float*)d_in[22];
    const float* hn      = (const float*)d_in[23];
    const float* out_w   = (const float*)d_in[24];
    const float* out_b   = (const float*)d_in[25];

    float* ws    = (float*)d_ws;
    float* c1    = ws;                       // 64*16*64*64 = 4194304 floats
    float* c     = c1 + 4194304;             // 64*256
    float* S     = c + 16384;                // 64*8
    float* lasth = S + 512;                  // 8*64*256
    // After conv2, the c1 region is dead; reuse it for converted weights.
    unsigned int* whh_h = (unsigned int*)c1;           // 262144 u32 = 1 MB
    unsigned int* bx    = whh_h + 262144;              // 4096 u32

    k_conv1<<<1024, 256, 0, stream>>>(x, conv1_w, conv1_b, bn1_g, bn1_b, bn1_m, bn1_v, c1);
    k_conv2<<<64, 256, 0, stream>>>(c1, conv2_w, conv2_b, bn2_g, bn2_b, bn2_m, bn2_v, c);
    k_mlp<<<64, 64, 0, stream>>>(c, pre_w1, pre_b1, pre_w2, pre_b2, pre_w3, pre_b3, S);
    k_cvt<<<1024, 256, 0, stream>>>(lstm_whh, whh_h);
    k_bx<<<16, 256, 0, stream>>>(lstm_wih, lstm_bih, lstm_bhh, bx);
    k_lstm<<<32, 512, 0, stream>>>(whh_h, bx, hn, c, lasth);
    k_out<<<64, 256, 0, stream>>>(lasth, S, out_w, out_b, (float*)d_out);
}